// Round 21
// baseline (47308.386 us; speedup 1.0000x reference)
//
#include <hip/hip_runtime.h>

// SNN forward — bitwise f32 BLAS-replication, cell: kc=512 K-panels {512,512}.
// Hypothesis: container numpy = OpenBLAS (DYNAMIC_ARCH -> ZEN target) whose
// SGEMM_DEFAULT_Q = 512. Per C element: ascending FMA chain within each
// 512-wide k-panel, panels combined with plain f32 adds (beta=0 first panel).
// Elementwise membrane math in the reference's exact f32 association order.
// (kc=256 was the closest cell at 0.1289; {1024} 0.1738 — this bisects.)

#pragma clang fp contract(off)

#define HDIM 1024
#define BATCH 16384
#define NSTEP 25
#define BM 128
#define BK 16
#define KC 512  // cell under test: {512,512} K-panels

enum { EPI_CUR = 0, EPI_DOT = 1, EPI_L1 = 2, EPI_L2 = 3 };

// stage tile rows [0..127], k in [kt*16, kt*16+16) -> s[k][row]  (s = [16][128] f32)
__device__ __forceinline__ void stage_f32(const float* __restrict__ g, float* s,
                                          int tid, int kt) {
  int row = tid & 127, c = tid >> 7;  // c in 0..1
  const float* src = g + (size_t)row * HDIM + kt * BK + c * 8;
  float4 v0 = *(const float4*)(src);
  float4 v1 = *(const float4*)(src + 4);
  int k0 = c * 8;
  s[(k0 + 0) * BM + row] = v0.x; s[(k0 + 1) * BM + row] = v0.y;
  s[(k0 + 2) * BM + row] = v0.z; s[(k0 + 3) * BM + row] = v0.w;
  s[(k0 + 4) * BM + row] = v1.x; s[(k0 + 5) * BM + row] = v1.y;
  s[(k0 + 6) * BM + row] = v1.z; s[(k0 + 7) * BM + row] = v1.w;
}

__device__ __forceinline__ void stage_u8(const unsigned char* __restrict__ g, float* s,
                                         int tid, int kt) {
  int row = tid & 127, c = tid >> 7;
  unsigned long long v =
      *(const unsigned long long*)(g + (size_t)row * HDIM + kt * BK + c * 8);
  int k0 = c * 8;
#pragma unroll
  for (int q = 0; q < 8; ++q)
    s[(k0 + q) * BM + row] = (float)((v >> (8 * q)) & 0xFFull);
}

// C[row,col] = sum_k A[row,k]*B[col,k] with kc=512 panel rounding:
// ascending FMA chain within each 512-panel; panels combined with f32 adds.
template <int EPI, bool AU8>
__global__ __launch_bounds__(256) void gemm_blas(
    const void* __restrict__ Av, const float* __restrict__ B,
    const float* __restrict__ bias,  // CUR: b1 ; L2: b2
    const float* __restrict__ vb,    // L1: V1b ; L2: V2b
    const float* __restrict__ aux,   // L1: cur1[idx] ; L2: rec2[idx]
    float* __restrict__ memv,        // CUR: cur1 out ; DOT: rec2 out ; L1: mem1 ; L2: mem2
    unsigned char* __restrict__ spk_out,
    unsigned char* __restrict__ ssum) {
  __shared__ float sA[BK * BM];
  __shared__ float sB[BK * BM];
  const int tid = threadIdx.x;
  const int m0 = (tid & 15) * 8, n0 = (tid >> 4) * 8;
  const int bm = blockIdx.y, bn = blockIdx.x;

  float csum[8][8] = {};  // accumulated panels
  float p[8][8] = {};     // current panel chain
  const float* Af = (const float*)Av;
  const unsigned char* Au = (const unsigned char*)Av;

#pragma unroll 1
  for (int kt = 0; kt < HDIM / BK; ++kt) {
    if (AU8) stage_u8(Au + (size_t)bm * BM * HDIM, sA, tid, kt);
    else     stage_f32(Af + (size_t)bm * BM * HDIM, sA, tid, kt);
    stage_f32(B + (size_t)bn * BM * HDIM, sB, tid, kt);
    __syncthreads();
#pragma unroll
    for (int k = 0; k < BK; ++k) {
      float a[8], b[8];
      *(float4*)&a[0] = *(const float4*)&sA[k * BM + m0];
      *(float4*)&a[4] = *(const float4*)&sA[k * BM + m0 + 4];
      *(float4*)&b[0] = *(const float4*)&sB[k * BM + n0];
      *(float4*)&b[4] = *(const float4*)&sB[k * BM + n0 + 4];
#pragma unroll
      for (int m = 0; m < 8; ++m)
#pragma unroll
        for (int n = 0; n < 8; ++n)
          p[m][n] = __builtin_fmaf(a[m], b[n], p[m][n]);
    }
    int kend = (kt + 1) * BK;
    if (kend % KC == 0) {  // panel boundary: C += panel (f32 add)
#pragma unroll
      for (int m = 0; m < 8; ++m)
#pragma unroll
        for (int n = 0; n < 8; ++n) {
          csum[m][n] = csum[m][n] + p[m][n];
          p[m][n] = 0.0f;
        }
    }
    __syncthreads();
  }

#pragma unroll
  for (int m = 0; m < 8; ++m) {
    int row = bm * BM + m0 + m;
#pragma unroll
    for (int n = 0; n < 8; ++n) {
      int col = bn * BM + n0 + n;
      size_t idx = (size_t)row * HDIM + col;
      float dot = csum[m][n];
      if constexpr (EPI == EPI_CUR) {
        memv[idx] = dot + bias[col];            // cur1 = x@W1.T + b1
      } else if constexpr (EPI == EPI_DOT) {
        memv[idx] = dot;                        // rec2 = spk2@V2w.T
      } else if constexpr (EPI == EPI_L1) {
        float mold = memv[idx];
        float reset = (mold > 1.0f) ? 1.0f : 0.0f;
        float t = 0.5f * mold;                  // BETA*mem1 (exact)
        t = t + aux[idx];                       // + cur1
        t = t + dot;                            // + spk1@V1w.T
        t = t + vb[col];                        // + V1b
        t = t - reset;                          // - reset1*THR
        memv[idx] = t;
        spk_out[idx] = ((t - 1.0f) > 0.0f) ? 1 : 0;
      } else {                                  // EPI_L2
        float mold = memv[idx];
        float reset = (mold > 1.0f) ? 1.0f : 0.0f;
        float cur2 = dot + bias[col];           // cur2 = spk1@W2.T + b2 (own rounding)
        float t = 0.5f * mold;
        t = t + cur2;
        t = t + aux[idx];                       // + rec2
        t = t + vb[col];                        // + V2b
        t = t - reset;
        memv[idx] = t;
        unsigned char s = ((t - 1.0f) > 0.0f) ? 1 : 0;
        spk_out[idx] = s;
        ssum[idx] = (unsigned char)(ssum[idx] + s);
      }
    }
  }
}

// out[b,o] = ((ssum[b,:]/25) . W3[o,:]) + b3[o], same kc=512 panel rounding.
__global__ __launch_bounds__(256) void out_blas(const unsigned char* __restrict__ ssum,
                                                const float* __restrict__ W3,
                                                const float* __restrict__ b3,
                                                float* __restrict__ out) {
  int t = blockIdx.x * 256 + threadIdx.x;
  int b = t >> 4, o = t & 15;
  if (o >= 10) return;
  const unsigned char* sp = ssum + (size_t)b * HDIM;
  const float* wp = W3 + (size_t)o * HDIM;
  float csum = 0.0f, p = 0.0f;
#pragma unroll 4
  for (int k = 0; k < HDIM; ++k) {
    float sv = (float)sp[k] / 25.0f;            // f32 elementwise divide (np order)
    p = __builtin_fmaf(sv, wp[k], p);
    if ((k + 1) % KC == 0) { csum = csum + p; p = 0.0f; }
  }
  out[(size_t)b * 10 + o] = csum + b3[o];
}

extern "C" void kernel_launch(void* const* d_in, const int* in_sizes, int n_in,
                              void* d_out, int out_size, void* d_ws, size_t ws_size,
                              hipStream_t stream) {
  const float* x = (const float*)d_in[0];
  const float* W1 = (const float*)d_in[1];
  const float* b1 = (const float*)d_in[2];
  const float* V1w = (const float*)d_in[3];
  const float* V1b = (const float*)d_in[4];
  const float* W2 = (const float*)d_in[5];
  const float* b2 = (const float*)d_in[6];
  const float* V2w = (const float*)d_in[7];
  const float* V2b = (const float*)d_in[8];
  const float* W3 = (const float*)d_in[9];
  const float* b3 = (const float*)d_in[10];
  float* out = (float*)d_out;

  char* ws = (char*)d_ws;
  // per-row: cur1, mem1, mem2, rec2 (f32) + 4 spike bufs + ssum (u8)
  const size_t per_row = (size_t)HDIM * 4 * 4 + (size_t)HDIM * 5;
  size_t rows = BATCH;
  while (rows > 128 && rows * per_row > ws_size) rows >>= 1;
  const int nchunk = (int)(BATCH / rows);
  const size_t RH = rows * (size_t)HDIM;

  size_t off = 0;
  float* cur1 = (float*)(ws + off); off += RH * 4;
  float* mem1 = (float*)(ws + off); off += RH * 4;
  float* mem2 = (float*)(ws + off); off += RH * 4;
  float* rec2 = (float*)(ws + off); off += RH * 4;
  unsigned char *spk1[2], *spk2[2];
  spk1[0] = (unsigned char*)(ws + off); off += RH;
  spk1[1] = (unsigned char*)(ws + off); off += RH;
  spk2[0] = (unsigned char*)(ws + off); off += RH;
  spk2[1] = (unsigned char*)(ws + off); off += RH;
  unsigned char* ssum = (unsigned char*)(ws + off); off += RH;

  dim3 grid(HDIM / BM, (unsigned)(rows / BM));

  for (int c = 0; c < nchunk; ++c) {
    const float* xc = x + (size_t)c * RH;
    float* outc = out + (size_t)c * rows * 10;

    hipMemsetAsync(mem1, 0, RH * 4, stream);
    hipMemsetAsync(mem2, 0, RH * 4, stream);
    hipMemsetAsync(ssum, 0, RH, stream);
    hipMemsetAsync(spk1[0], 0, RH, stream);
    hipMemsetAsync(spk2[0], 0, RH, stream);

    // cur1 = x@W1.T + b1 (loop-invariant, computed once)
    gemm_blas<EPI_CUR, false><<<grid, 256, 0, stream>>>(
        xc, W1, b1, nullptr, nullptr, cur1, nullptr, nullptr);

    for (int t = 0; t < NSTEP; ++t) {
      int rd = t & 1, wr = rd ^ 1;
      // layer 1: rec1 = spk1_prev @ V1w.T ; mem1/spk1 fused
      gemm_blas<EPI_L1, true><<<grid, 256, 0, stream>>>(
          spk1[rd], V1w, nullptr, V1b, cur1, mem1, spk1[wr], nullptr);
      // rec2 = spk2_prev @ V2w.T (separate rounding, like the reference)
      gemm_blas<EPI_DOT, true><<<grid, 256, 0, stream>>>(
          spk2[rd], V2w, nullptr, nullptr, nullptr, rec2, nullptr, nullptr);
      // layer 2: cur2 = spk1_new @ W2.T + b2 ; mem2/spk2/ssum fused
      gemm_blas<EPI_L2, true><<<grid, 256, 0, stream>>>(
          spk1[wr], W2, b2, V2b, rec2, mem2, spk2[wr], ssum);
    }
    out_blas<<<(unsigned)(rows * 16 / 256), 256, 0, stream>>>(ssum, W3, b3, outc);
  }
}

// Round 22
// 34164.029 us; speedup vs baseline: 1.3847x; 1.3847x over previous
//
#include <hip/hip_runtime.h>

// SNN forward — bitwise numpy/OpenBLAS(kc=512) f32 semantics (verified R21,
// absmax=0.0039): per C element an ascending-k f32 FMA chain with a panel
// break at k=512 (csum = p1 + p2), elementwise f32 in reference order.
// This round: performance retile (128x64, conflict-free LDS, coalesced
// epilogue) + fuse rec2 GEMM into the L2 kernel (independent chains).

#pragma clang fp contract(off)

#define HDIM 1024
#define BATCH 16384
#define NSTEP 25
#define BMR 128  // tile rows
#define BNC 64   // tile cols
#define BK 16
#define KC 512   // verified K-panel split {512,512}

// ---- staging: A f32 tile [16][128] ----
__device__ __forceinline__ void stage_a_f32(const float* __restrict__ g, float* s,
                                            int tid, int kt) {
  int row = tid & 127, c = tid >> 7;  // c in 0..1
  const float* src = g + (size_t)row * HDIM + kt * BK + c * 8;
  float4 v0 = *(const float4*)(src);
  float4 v1 = *(const float4*)(src + 4);
  int k0 = c * 8;
  s[(k0 + 0) * BMR + row] = v0.x; s[(k0 + 1) * BMR + row] = v0.y;
  s[(k0 + 2) * BMR + row] = v0.z; s[(k0 + 3) * BMR + row] = v0.w;
  s[(k0 + 4) * BMR + row] = v1.x; s[(k0 + 5) * BMR + row] = v1.y;
  s[(k0 + 6) * BMR + row] = v1.z; s[(k0 + 7) * BMR + row] = v1.w;
}

// ---- staging: A u8 (spike) tile [16][128] ----
__device__ __forceinline__ void stage_a_u8(const unsigned char* __restrict__ g, float* s,
                                           int tid, int kt) {
  int row = tid & 127, c = tid >> 7;
  unsigned long long v =
      *(const unsigned long long*)(g + (size_t)row * HDIM + kt * BK + c * 8);
  int k0 = c * 8;
#pragma unroll
  for (int q = 0; q < 8; ++q)
    s[(k0 + q) * BMR + row] = (float)((v >> (8 * q)) & 0xFFull);
}

// ---- staging: B (weights) tile [16][64] ----
__device__ __forceinline__ void stage_b(const float* __restrict__ g, float* s,
                                        int tid, int kt) {
  int row = tid & 63, c = tid >> 6;  // c in 0..3
  float4 v = *(const float4*)(g + (size_t)row * HDIM + kt * BK + c * 4);
  int k0 = c * 4;
  s[(k0 + 0) * BNC + row] = v.x; s[(k0 + 1) * BNC + row] = v.y;
  s[(k0 + 2) * BNC + row] = v.z; s[(k0 + 3) * BNC + row] = v.w;
}

// one K-pass: accumulate the kc=512-panel chain for a 4x8 micro-tile.
// m0 = (tid>>3)*4, n0 = (tid&7)*8.
template <bool AU8>
__device__ __forceinline__ void kpass(const void* __restrict__ Ag,
                                      const float* __restrict__ Bg,
                                      float* sA, float* sB, int tid, int m0, int n0,
                                      float csum[4][8]) {
  float p[4][8];
#pragma unroll
  for (int m = 0; m < 4; ++m)
#pragma unroll
    for (int n = 0; n < 8; ++n) { csum[m][n] = 0.0f; p[m][n] = 0.0f; }

#pragma unroll 1
  for (int kt = 0; kt < HDIM / BK; ++kt) {
    if (AU8) stage_a_u8((const unsigned char*)Ag, sA, tid, kt);
    else     stage_a_f32((const float*)Ag, sA, tid, kt);
    stage_b(Bg, sB, tid, kt);
    __syncthreads();
#pragma unroll
    for (int k = 0; k < BK; ++k) {
      float a[4], b[8];
      *(float4*)&a[0] = *(const float4*)&sA[k * BMR + m0];
      *(float4*)&b[0] = *(const float4*)&sB[k * BNC + n0];
      *(float4*)&b[4] = *(const float4*)&sB[k * BNC + n0 + 4];
#pragma unroll
      for (int m = 0; m < 4; ++m)
#pragma unroll
        for (int n = 0; n < 8; ++n)
          p[m][n] = __builtin_fmaf(a[m], b[n], p[m][n]);
    }
    if (((kt + 1) * BK) % KC == 0) {  // panel boundary: C += panel
#pragma unroll
      for (int m = 0; m < 4; ++m)
#pragma unroll
        for (int n = 0; n < 8; ++n) { csum[m][n] = csum[m][n] + p[m][n]; p[m][n] = 0.0f; }
    }
    __syncthreads();
  }
}

// cur1 = x@W1.T + b1
__global__ __launch_bounds__(256) void gemm_cur(const float* __restrict__ A,
                                                const float* __restrict__ B,
                                                const float* __restrict__ bias,
                                                float* __restrict__ outv) {
  __shared__ float sA[BK * BMR];
  __shared__ float sB[BK * BNC];
  const int tid = threadIdx.x;
  const int m0 = (tid >> 3) * 4, n0 = (tid & 7) * 8;
  const int bm = blockIdx.y, bn = blockIdx.x;
  float csum[4][8];
  kpass<false>(A + (size_t)bm * BMR * HDIM, B + (size_t)bn * BNC * HDIM,
               sA, sB, tid, m0, n0, csum);
  const int colb = bn * BNC + n0;
  float4 bia0 = *(const float4*)&bias[colb];
  float4 bia1 = *(const float4*)&bias[colb + 4];
  const float bi[8] = {bia0.x, bia0.y, bia0.z, bia0.w, bia1.x, bia1.y, bia1.z, bia1.w};
#pragma unroll
  for (int m = 0; m < 4; ++m) {
    size_t idx = (size_t)(bm * BMR + m0 + m) * HDIM + colb;
    float o[8];
#pragma unroll
    for (int n = 0; n < 8; ++n) o[n] = csum[m][n] + bi[n];
    *(float4*)&outv[idx] = *(float4*)&o[0];
    *(float4*)&outv[idx + 4] = *(float4*)&o[4];
  }
}

// layer1: rec1 = spk1p@V1w.T ; mem1 = 0.5*mem1 + cur1 + rec1 + V1b - reset
__global__ __launch_bounds__(256) void gemm_l1(
    const unsigned char* __restrict__ A, const float* __restrict__ B,
    const float* __restrict__ vb, const float* __restrict__ cur1,
    float* __restrict__ memv, unsigned char* __restrict__ spk_out) {
  __shared__ float sA[BK * BMR];
  __shared__ float sB[BK * BNC];
  const int tid = threadIdx.x;
  const int m0 = (tid >> 3) * 4, n0 = (tid & 7) * 8;
  const int bm = blockIdx.y, bn = blockIdx.x;
  float csum[4][8];
  kpass<true>(A + (size_t)bm * BMR * HDIM, B + (size_t)bn * BNC * HDIM,
              sA, sB, tid, m0, n0, csum);
  const int colb = bn * BNC + n0;
  float4 v0 = *(const float4*)&vb[colb];
  float4 v1 = *(const float4*)&vb[colb + 4];
  const float vbv[8] = {v0.x, v0.y, v0.z, v0.w, v1.x, v1.y, v1.z, v1.w};
#pragma unroll
  for (int m = 0; m < 4; ++m) {
    size_t row = (size_t)(bm * BMR + m0 + m);
    size_t idx = row * HDIM + colb;
    float mo[8], au[8], tn[8];
    *(float4*)&mo[0] = *(const float4*)&memv[idx];
    *(float4*)&mo[4] = *(const float4*)&memv[idx + 4];
    *(float4*)&au[0] = *(const float4*)&cur1[idx];
    *(float4*)&au[4] = *(const float4*)&cur1[idx + 4];
    unsigned long long sv = 0;
#pragma unroll
    for (int n = 0; n < 8; ++n) {
      float reset = (mo[n] > 1.0f) ? 1.0f : 0.0f;
      float t = 0.5f * mo[n];
      t = t + au[n];
      t = t + csum[m][n];
      t = t + vbv[n];
      t = t - reset;
      tn[n] = t;
      sv |= ((unsigned long long)(((t - 1.0f) > 0.0f) ? 1 : 0)) << (8 * n);
    }
    *(float4*)&memv[idx] = *(float4*)&tn[0];
    *(float4*)&memv[idx + 4] = *(float4*)&tn[4];
    *(unsigned long long*)&spk_out[idx] = sv;
  }
}

// layer2 fused: cur2 = spk1n@W2.T + b2 ; rec2 = spk2p@V2w.T ;
// mem2 = 0.5*mem2 + cur2 + rec2 + V2b - reset ; spk2/ssum out.
__global__ __launch_bounds__(256) void gemm_l2f(
    const unsigned char* __restrict__ A1, const float* __restrict__ B1,
    const unsigned char* __restrict__ A2, const float* __restrict__ B2,
    const float* __restrict__ bias, const float* __restrict__ vb,
    float* __restrict__ memv, unsigned char* __restrict__ spk_out,
    unsigned char* __restrict__ ssum) {
  __shared__ float sA[BK * BMR];
  __shared__ float sB[BK * BNC];
  const int tid = threadIdx.x;
  const int m0 = (tid >> 3) * 4, n0 = (tid & 7) * 8;
  const int bm = blockIdx.y, bn = blockIdx.x;
  float dot1[4][8], csum[4][8];
  kpass<true>(A1 + (size_t)bm * BMR * HDIM, B1 + (size_t)bn * BNC * HDIM,
              sA, sB, tid, m0, n0, csum);
#pragma unroll
  for (int m = 0; m < 4; ++m)
#pragma unroll
    for (int n = 0; n < 8; ++n) dot1[m][n] = csum[m][n];
  __syncthreads();
  kpass<true>(A2 + (size_t)bm * BMR * HDIM, B2 + (size_t)bn * BNC * HDIM,
              sA, sB, tid, m0, n0, csum);  // csum = rec2 chain
  const int colb = bn * BNC + n0;
  float4 b0 = *(const float4*)&bias[colb];
  float4 b1v = *(const float4*)&bias[colb + 4];
  const float bi[8] = {b0.x, b0.y, b0.z, b0.w, b1v.x, b1v.y, b1v.z, b1v.w};
  float4 v0 = *(const float4*)&vb[colb];
  float4 v1 = *(const float4*)&vb[colb + 4];
  const float vbv[8] = {v0.x, v0.y, v0.z, v0.w, v1.x, v1.y, v1.z, v1.w};
#pragma unroll
  for (int m = 0; m < 4; ++m) {
    size_t row = (size_t)(bm * BMR + m0 + m);
    size_t idx = row * HDIM + colb;
    float mo[8], tn[8];
    *(float4*)&mo[0] = *(const float4*)&memv[idx];
    *(float4*)&mo[4] = *(const float4*)&memv[idx + 4];
    unsigned long long sv = 0;
#pragma unroll
    for (int n = 0; n < 8; ++n) {
      float reset = (mo[n] > 1.0f) ? 1.0f : 0.0f;
      float cur2 = dot1[m][n] + bi[n];
      float t = 0.5f * mo[n];
      t = t + cur2;
      t = t + csum[m][n];
      t = t + vbv[n];
      t = t - reset;
      tn[n] = t;
      sv |= ((unsigned long long)(((t - 1.0f) > 0.0f) ? 1 : 0)) << (8 * n);
    }
    *(float4*)&memv[idx] = *(float4*)&tn[0];
    *(float4*)&memv[idx + 4] = *(float4*)&tn[4];
    *(unsigned long long*)&spk_out[idx] = sv;
    unsigned long long old = *(unsigned long long*)&ssum[idx];
    unsigned long long ns = 0;
#pragma unroll
    for (int n = 0; n < 8; ++n) {
      unsigned char c = (unsigned char)(((old >> (8 * n)) & 0xFF) + ((sv >> (8 * n)) & 1));
      ns |= ((unsigned long long)c) << (8 * n);
    }
    *(unsigned long long*)&ssum[idx] = ns;
  }
}

// out[b,o] = ((ssum[b,:]/25) . W3[o,:]) + b3[o], kc=512 panel rounding.
__global__ __launch_bounds__(256) void out_blas(const unsigned char* __restrict__ ssum,
                                                const float* __restrict__ W3,
                                                const float* __restrict__ b3,
                                                float* __restrict__ out) {
  int t = blockIdx.x * 256 + threadIdx.x;
  int b = t >> 4, o = t & 15;
  if (o >= 10) return;
  const unsigned char* sp = ssum + (size_t)b * HDIM;
  const float* wp = W3 + (size_t)o * HDIM;
  float csum = 0.0f, p = 0.0f;
#pragma unroll 4
  for (int k = 0; k < HDIM; ++k) {
    float sv = (float)sp[k] / 25.0f;
    p = __builtin_fmaf(sv, wp[k], p);
    if ((k + 1) % KC == 0) { csum = csum + p; p = 0.0f; }
  }
  out[(size_t)b * 10 + o] = csum + b3[o];
}

extern "C" void kernel_launch(void* const* d_in, const int* in_sizes, int n_in,
                              void* d_out, int out_size, void* d_ws, size_t ws_size,
                              hipStream_t stream) {
  const float* x = (const float*)d_in[0];
  const float* W1 = (const float*)d_in[1];
  const float* b1 = (const float*)d_in[2];
  const float* V1w = (const float*)d_in[3];
  const float* V1b = (const float*)d_in[4];
  const float* W2 = (const float*)d_in[5];
  const float* b2 = (const float*)d_in[6];
  const float* V2w = (const float*)d_in[7];
  const float* V2b = (const float*)d_in[8];
  const float* W3 = (const float*)d_in[9];
  const float* b3 = (const float*)d_in[10];
  float* out = (float*)d_out;

  char* ws = (char*)d_ws;
  // per-row: cur1, mem1, mem2 (f32) + 4 spike bufs + ssum (u8)
  const size_t per_row = (size_t)HDIM * 4 * 3 + (size_t)HDIM * 5;
  size_t rows = BATCH;
  while (rows > 128 && rows * per_row > ws_size) rows >>= 1;
  const int nchunk = (int)(BATCH / rows);
  const size_t RH = rows * (size_t)HDIM;

  size_t off = 0;
  float* cur1 = (float*)(ws + off); off += RH * 4;
  float* mem1 = (float*)(ws + off); off += RH * 4;
  float* mem2 = (float*)(ws + off); off += RH * 4;
  unsigned char *spk1[2], *spk2[2];
  spk1[0] = (unsigned char*)(ws + off); off += RH;
  spk1[1] = (unsigned char*)(ws + off); off += RH;
  spk2[0] = (unsigned char*)(ws + off); off += RH;
  spk2[1] = (unsigned char*)(ws + off); off += RH;
  unsigned char* ssum = (unsigned char*)(ws + off); off += RH;

  dim3 grid(HDIM / BNC, (unsigned)(rows / BMR));  // (16, rows/128)

  for (int c = 0; c < nchunk; ++c) {
    const float* xc = x + (size_t)c * RH;
    float* outc = out + (size_t)c * rows * 10;

    hipMemsetAsync(mem1, 0, RH * 4, stream);
    hipMemsetAsync(mem2, 0, RH * 4, stream);
    hipMemsetAsync(ssum, 0, RH, stream);
    hipMemsetAsync(spk1[0], 0, RH, stream);
    hipMemsetAsync(spk2[0], 0, RH, stream);

    // cur1 = x@W1.T + b1 (loop-invariant)
    gemm_cur<<<grid, 256, 0, stream>>>(xc, W1, b1, cur1);

    for (int t = 0; t < NSTEP; ++t) {
      int rd = t & 1, wr = rd ^ 1;
      gemm_l1<<<grid, 256, 0, stream>>>(spk1[rd], V1w, V1b, cur1, mem1, spk1[wr]);
      gemm_l2f<<<grid, 256, 0, stream>>>(spk1[wr], W2, spk2[rd], V2w, b2, V2b,
                                         mem2, spk2[wr], ssum);
    }
    out_blas<<<(unsigned)(rows * 16 / 256), 256, 0, stream>>>(ssum, W3, b3, outc);
  }
}